// Round 3
// baseline (489.803 us; speedup 1.0000x reference)
//
#include <hip/hip_runtime.h>

// Max-unpooling scatter with numpy last-write-wins duplicate semantics.
// in  x:   (32,56,56,64)  fp32  = 6,422,528 elems
// in  pos: (32,56,56,64)  int32 in [0, N_OUT)
// out:     (32,112,112,64) fp32 = 25,690,112 elems
//
// Strategy: d_out doubles as an int32 "winner index" buffer.
//   pass1: memset d_out to 0xFF (= -1 as int32)
//   pass2: atomicMax(winner[pos[i]], i)  -- max flat index == numpy last-write-wins
//   pass3: out[j] = (winner[j] < 0) ? 0.0f : x[winner[j]]   (in-place, vectorized)

#define N_IN   6422528
#define N_OUT  25690112

__global__ __launch_bounds__(256) void scatter_idx_kernel(
        const int* __restrict__ pos, int* __restrict__ winner) {
    const int4* __restrict__ pos4 = reinterpret_cast<const int4*>(pos);
    const int n4 = N_IN / 4;  // 1,605,632
    int stride = gridDim.x * blockDim.x;
    for (int i = blockIdx.x * blockDim.x + threadIdx.x; i < n4; i += stride) {
        int4 p = pos4[i];
        int base = i * 4;
        atomicMax(&winner[p.x], base + 0);
        atomicMax(&winner[p.y], base + 1);
        atomicMax(&winner[p.z], base + 2);
        atomicMax(&winner[p.w], base + 3);
    }
}

__global__ __launch_bounds__(256) void resolve_kernel(
        const float* __restrict__ x, float* __restrict__ out) {
    const int n4 = N_OUT / 4;  // 6,422,528
    int stride = gridDim.x * blockDim.x;
    for (int i = blockIdx.x * blockDim.x + threadIdx.x; i < n4; i += stride) {
        int4 v = reinterpret_cast<const int4*>(out)[i];
        float4 r;
        r.x = (v.x < 0) ? 0.0f : x[v.x];
        r.y = (v.y < 0) ? 0.0f : x[v.y];
        r.z = (v.z < 0) ? 0.0f : x[v.z];
        r.w = (v.w < 0) ? 0.0f : x[v.w];
        reinterpret_cast<float4*>(out)[i] = r;
    }
}

extern "C" void kernel_launch(void* const* d_in, const int* in_sizes, int n_in,
                              void* d_out, int out_size, void* d_ws, size_t ws_size,
                              hipStream_t stream) {
    const float* x  = (const float*)d_in[0];
    const int*  pos = (const int*)d_in[1];
    float* out = (float*)d_out;

    // pass1: init winner buffer to -1 (0xFFFFFFFF)
    hipMemsetAsync(d_out, 0xFF, (size_t)N_OUT * sizeof(int), stream);

    // pass2: scatter max input index
    scatter_idx_kernel<<<2048, 256, 0, stream>>>(pos, (int*)d_out);

    // pass3: convert winner index -> value (in place), zeros elsewhere
    resolve_kernel<<<2048, 256, 0, stream>>>(x, out);
}

// Round 4
// 436.612 us; speedup vs baseline: 1.1218x; 1.1218x over previous
//
#include <hip/hip_runtime.h>

// Max-unpooling scatter, numpy last-write-wins duplicate semantics.
// in  x:   (32,56,56,64)  fp32  = 6,422,528
// in  pos: (32,56,56,64)  int32 in [0, N_OUT)
// out:     (32,112,112,64) fp32 = 25,690,112
//
// Fast path (needs ws >= N_OUT*8 bytes):
//   pass1: memset d_ws to 0
//   pass2: atomicMax(pair[pos[i]], ((u64)(i+1)<<32) | bits(x[i]))
//          -- high-word index ordering == numpy last-write-wins, value rides along
//   pass3: out[j] = pair[j] ? low32-as-float : 0   (pure streaming, no gather)
// Fallback (small ws): winner-index scatter into d_out + gather resolve.

#define N_IN   6422528
#define N_OUT  25690112

__global__ __launch_bounds__(256) void scatter_pair_kernel(
        const float* __restrict__ x, const int* __restrict__ pos,
        unsigned long long* __restrict__ pair) {
    const int4*   __restrict__ pos4 = reinterpret_cast<const int4*>(pos);
    const float4* __restrict__ x4   = reinterpret_cast<const float4*>(x);
    const int n4 = N_IN / 4;  // 1,605,632
    int stride = gridDim.x * blockDim.x;
    for (int i = blockIdx.x * blockDim.x + threadIdx.x; i < n4; i += stride) {
        int4 p   = pos4[i];
        float4 v = x4[i];
        unsigned long long b = ((unsigned long long)(4u * (unsigned)i + 1u)) << 32;
        atomicMax(&pair[p.x],  b                          | (unsigned long long)__float_as_uint(v.x));
        atomicMax(&pair[p.y], (b + (1ull << 32))          | (unsigned long long)__float_as_uint(v.y));
        atomicMax(&pair[p.z], (b + (2ull << 32))          | (unsigned long long)__float_as_uint(v.z));
        atomicMax(&pair[p.w], (b + (3ull << 32))          | (unsigned long long)__float_as_uint(v.w));
    }
}

__global__ __launch_bounds__(256) void resolve_pair_kernel(
        const unsigned long long* __restrict__ pair, float* __restrict__ out) {
    const int n4 = N_OUT / 4;  // 6,422,528
    int stride = gridDim.x * blockDim.x;
    for (int i = blockIdx.x * blockDim.x + threadIdx.x; i < n4; i += stride) {
        ulonglong2 a = reinterpret_cast<const ulonglong2*>(pair)[2 * i];
        ulonglong2 c = reinterpret_cast<const ulonglong2*>(pair)[2 * i + 1];
        float4 r;
        r.x = a.x ? __uint_as_float((unsigned)a.x) : 0.0f;
        r.y = a.y ? __uint_as_float((unsigned)a.y) : 0.0f;
        r.z = c.x ? __uint_as_float((unsigned)c.x) : 0.0f;
        r.w = c.y ? __uint_as_float((unsigned)c.y) : 0.0f;
        reinterpret_cast<float4*>(out)[i] = r;
    }
}

// ---- fallback path (ws too small): proven round-3 scheme ----
__global__ __launch_bounds__(256) void scatter_idx_kernel(
        const int* __restrict__ pos, int* __restrict__ winner) {
    const int4* __restrict__ pos4 = reinterpret_cast<const int4*>(pos);
    const int n4 = N_IN / 4;
    int stride = gridDim.x * blockDim.x;
    for (int i = blockIdx.x * blockDim.x + threadIdx.x; i < n4; i += stride) {
        int4 p = pos4[i];
        int base = i * 4;
        atomicMax(&winner[p.x], base + 0);
        atomicMax(&winner[p.y], base + 1);
        atomicMax(&winner[p.z], base + 2);
        atomicMax(&winner[p.w], base + 3);
    }
}

__global__ __launch_bounds__(256) void resolve_kernel(
        const float* __restrict__ x, float* __restrict__ out) {
    const int n4 = N_OUT / 4;
    int stride = gridDim.x * blockDim.x;
    for (int i = blockIdx.x * blockDim.x + threadIdx.x; i < n4; i += stride) {
        int4 v = reinterpret_cast<const int4*>(out)[i];
        float4 r;
        r.x = (v.x < 0) ? 0.0f : x[v.x];
        r.y = (v.y < 0) ? 0.0f : x[v.y];
        r.z = (v.z < 0) ? 0.0f : x[v.z];
        r.w = (v.w < 0) ? 0.0f : x[v.w];
        reinterpret_cast<float4*>(out)[i] = r;
    }
}

extern "C" void kernel_launch(void* const* d_in, const int* in_sizes, int n_in,
                              void* d_out, int out_size, void* d_ws, size_t ws_size,
                              hipStream_t stream) {
    const float* x  = (const float*)d_in[0];
    const int*  pos = (const int*)d_in[1];
    float* out = (float*)d_out;

    const size_t pair_bytes = (size_t)N_OUT * sizeof(unsigned long long);  // ~206 MB
    if (ws_size >= pair_bytes) {
        unsigned long long* pair = (unsigned long long*)d_ws;
        hipMemsetAsync(d_ws, 0, pair_bytes, stream);
        scatter_pair_kernel<<<2048, 256, 0, stream>>>(x, pos, pair);
        resolve_pair_kernel<<<2048, 256, 0, stream>>>(pair, out);
    } else {
        hipMemsetAsync(d_out, 0xFF, (size_t)N_OUT * sizeof(int), stream);
        scatter_idx_kernel<<<2048, 256, 0, stream>>>(pos, (int*)d_out);
        resolve_kernel<<<2048, 256, 0, stream>>>(x, out);
    }
}